// Round 11
// baseline (3194.215 us; speedup 1.0000x reference)
//
#include <hip/hip_runtime.h>

#define NN 10368
#define EE 207360
#define TT 16

// ---- workspace layout (float offsets) ---- persistent end = 6,184,336 floats = 24.74 MB
#define O_W0AT    0
#define O_W0BT    9216
#define O_GB      18432
#define O_LOSS    18816
#define O_H       18832
#define O_C       (O_H  + NN*96)
#define O_A       (O_C  + NN*96)
#define O_BV      (O_A  + NN*96)
#define O_S2      (O_BV + NN*96)
#define O_X       (O_S2 + NN*96)
#define O_WFRAG   (O_X  + NN*96)      // edge frags: 55296 shorts = 27648 floats
#define O_GF      (O_WFRAG + 27648)   // gate frags: 3mat x 3lev x 72tiles x 512 shorts = 165888 floats
// prep-only aliases into S2 (written by k_convert, consumed by k_input, dead before k_edge):
#define O_WIN0T   (O_S2)              // 4608
#define O_WINT    (O_S2 + 4608)       // 27648

using bf16x8 = __attribute__((ext_vector_type(8))) short;
using f32x4  = __attribute__((ext_vector_type(4))) float;

__device__ __forceinline__ float sigm(float x){ return 1.f/(1.f + expf(-x)); }

__device__ __forceinline__ unsigned rne_bf16(float f){
  unsigned u = __float_as_uint(f);
  u += 0x7fffu + ((u >> 16) & 1u);
  return u >> 16;
}
__device__ __forceinline__ void split3(float x, short& h, short& m, short& l){
  unsigned uh = rne_bf16(x); h = (short)uh;
  float fh = __uint_as_float(uh << 16);
  float r1 = x - fh;
  unsigned um = rne_bf16(r1); m = (short)um;
  float fm = __uint_as_float(um << 16);
  float r2 = r1 - fm;
  l = (short)rne_bf16(r2);
}

// ---------- prep: weight transposes + loss zero ----------
__global__ void k_convert(float* ws, const float* msgW0,
                          const float* inW0, const float* inW)
{
  int i = blockIdx.x*256 + threadIdx.x;
  if (i < 9216){ int k=i/96, j=i%96; ws[O_W0AT+i] = msgW0[j*192+k];    return; } i -= 9216;
  if (i < 9216){ int k=i/96, j=i%96; ws[O_W0BT+i] = msgW0[j*192+96+k]; return; } i -= 9216;
  if (i < 4608){ int k=i/96, j=i%96; ws[O_WIN0T+i] = inW0[j*48+k];     return; } i -= 4608;
  if (i < 27648){ int l=i/9216, r=i%9216; int k=r/96, j=r%96;
                  ws[O_WINT+i] = inW[l*9216 + j*96 + k];               return; } i -= 27648;
  if (i == 0){ ws[O_LOSS] = 0.f; }
}

// ---------- gate bias fold: GB = 20 * W_ihm @ msg_b[3] ----------
__global__ void k_gb(float* ws, const float* Wih, const float* msgb)
{
  int j = blockIdx.x*256 + threadIdx.x;
  if (j >= 384) return;
  float g = 0.f;
  for (int r=0;r<96;r++) g = fmaf(Wih[j*192+96+r], msgb[288+r], g);
  ws[O_GB + j] = 20.f * g;
}

// ---------- gate weight frags: 3 matrices, each [384 x 96] row-major, k_wfrag-verbatim ----------
// mat0 = Wih[:, :96] (x term), mat1 = Wcomb = W_ihm @ msg_W[2] (s2 term), mat2 = Whh (h term)
// frag element: B[k=quad*8+j][n=(lane&15)+16*nt] = W[nout][k], k = 32*kt + quad*8 + j
// storage idx = ((mat*3+lev)*72 + nt*3+kt)*64 + lane
__global__ void k_gfrag(float* ws, const float* Wih, const float* Whh, const float* msgW)
{
  int idx = blockIdx.x*256 + threadIdx.x;
  if (idx >= 3*3*72*64) return;
  int lane = idx & 63;
  int tile = (idx >> 6) % 72;
  int lev  = (idx >> 6) / 72 % 3;
  int mat  = (idx >> 6) / 216;
  int nt = tile/3, kt = tile%3;
  int nout = (lane & 15) + 16*nt;
  int q = lane >> 4;
  unsigned short* dstp = (unsigned short*)(ws + O_GF) + (size_t)idx*8;
  for (int j=0;j<8;j++){
    int k = 32*kt + 8*q + j;
    float wv;
    if (mat == 0)      wv = Wih[nout*192 + k];
    else if (mat == 2) wv = Whh[nout*96 + k];
    else {
      float a = 0.f;
      for (int r=0;r<96;r++) a = fmaf(Wih[nout*192+96+r], msgW[2*9216 + r*96 + k], a);
      wv = a;
    }
    short h,m,l; split3(wv, h, m, l);
    dstp[j] = (unsigned short)(lev==0 ? h : (lev==1 ? m : l));
  }
}

// ---------- msg W1/W2 -> bf16 split-3 B-fragments (edge kernel, verified) ----------
__global__ void k_wfrag(float* ws, const float* msgW)
{
  int idx = blockIdx.x*256 + threadIdx.x;
  if (idx >= 2*3*18*64) return;
  int lane = idx & 63;
  int tile = (idx >> 6) % 18;
  int lev  = (idx >> 6) / 18 % 3;
  int layer= (idx >> 6) / 54;
  int nt = tile/3, kt = tile%3;
  int nout = (lane & 15) + 16*nt;
  int q = lane >> 4;
  unsigned short* wf = (unsigned short*)(ws + O_WFRAG);
  unsigned short* dstp = wf + (size_t)(((layer*3+lev)*18 + tile)*64 + lane)*8;
  const float* W = msgW + layer*9216;
  for (int j=0;j<8;j++){
    float wv = W[nout*96 + 32*kt + 8*q + j];
    short h,m,l; split3(wv, h, m, l);
    dstp[j] = (unsigned short)(lev==0 ? h : (lev==1 ? m : l));
  }
}

// ---------- input MLP (j-parallel) + fused step-0 A/B (verified r7/r10) ----------
__global__ __launch_bounds__(192) void k_input(float* ws,
    const int* q, const int* row, const int* col,
    const float* demb, const float* remb, const float* cemb,
    const float* inb, const float* msgb)
{
  __shared__ float ein[2][8*49];
  __shared__ float hb[2][8*97];
  int tid = threadIdx.x; int g = tid/96, j = tid%96;
  int nq = blockIdx.x*2 + g; int n0 = nq*8;

  for (int idx=j; idx<384; idx+=96){
    int i = idx/48, f = idx%48; int n = n0+i;
    float v;
    if (f < 16)      v = demb[q[n]*16 + f];
    else if (f < 32) v = remb[row[n]*16 + (f-16)];
    else             v = cemb[col[n]*16 + (f-32)];
    ein[g][i*49+f] = v;
  }
  __syncthreads();

  float acc[8];
  {
    const float* W0T = ws + O_WIN0T;
    float b0 = inb[j];
    #pragma unroll
    for (int i=0;i<8;i++) acc[i]=b0;
    #pragma unroll 2
    for (int k=0;k<48;k++){
      float w = W0T[k*96+j];
      #pragma unroll
      for (int i=0;i<8;i++) acc[i] = fmaf(w, ein[g][i*49+k], acc[i]);
    }
    #pragma unroll
    for (int i=0;i<8;i++) hb[g][i*97+j] = fmaxf(acc[i], 0.f);
  }
  __syncthreads();

  for (int l=0;l<3;l++){
    const float* WT = ws + O_WINT + l*9216;
    float bl = inb[(l+1)*96 + j];
    #pragma unroll
    for (int i=0;i<8;i++) acc[i]=bl;
    #pragma unroll 2
    for (int k=0;k<96;k++){
      float w = WT[k*96+j];
      #pragma unroll
      for (int i=0;i<8;i++) acc[i] = fmaf(w, hb[g][i*97+k], acc[i]);
    }
    __syncthreads();
    if (l < 2){
      #pragma unroll
      for (int i=0;i<8;i++) hb[g][i*97+j] = fmaxf(acc[i], 0.f);
    } else {
      #pragma unroll
      for (int i=0;i<8;i++) hb[g][i*97+j] = acc[i];
    }
    __syncthreads();
  }

  float* h = ws + O_H; float* c = ws + O_C; float* x = ws + O_X;
  #pragma unroll
  for (int i=0;i<8;i++){
    int n = n0+i;
    float vv = hb[g][i*97+j];
    h[n*96+j]=vv; x[n*96+j]=vv; c[n*96+j]=0.f;
  }
  const float* WA = ws + O_W0AT; const float* WB = ws + O_W0BT;
  float aa[8], ab[8];
  #pragma unroll
  for (int i=0;i<8;i++){ aa[i]=0.f; ab[i]=0.f; }
  #pragma unroll 2
  for (int k=0;k<96;k++){
    float wa=WA[k*96+j], wb=WB[k*96+j];
    #pragma unroll
    for (int i=0;i<8;i++){
      float hv = hb[g][i*97+k];
      aa[i]=fmaf(wa,hv,aa[i]); ab[i]=fmaf(wb,hv,ab[i]);
    }
  }
  float* A=ws+O_A; float* Bv=ws+O_BV;
  float b0v = msgb[j];
  #pragma unroll
  for (int i=0;i<8;i++){ int n=n0+i; A[n*96+j]=aa[i]; Bv[n*96+j]=ab[i]+b0v; }
}

// ---------- per-step edge MLP via bf16 split-3 MFMA, 4 nodes/block (verified r7/r10) ----------
__global__ __launch_bounds__(320) void k_edge(float* ws, const int* dst, const float* msgb)
{
  __shared__ float tile[5][16*100];
  __shared__ float part[5][2][96];
  int w = threadIdx.x >> 6;
  int L = threadIdx.x & 63;
  int m = L & 15, q = L >> 4;
  int gs = w*16 + m;
  int e  = blockIdx.x*80 + gs;
  int v  = dst[e];
  int n  = blockIdx.x*4 + gs/20;

  const float* Aact = ws + O_A;
  const float* Bact = ws + O_BV;
  const unsigned short* wf = (const unsigned short*)(ws + O_WFRAG);

  bf16x8 aH[3], aM[3], aL[3];
  #pragma unroll
  for (int kt=0; kt<3; kt++){
    int k0 = 32*kt + 8*q;
    float4 a0 = *(const float4*)(Aact + (size_t)v*96 + k0);
    float4 a1 = *(const float4*)(Aact + (size_t)v*96 + k0 + 4);
    float4 b0 = *(const float4*)(Bact + (size_t)n*96 + k0);
    float4 b1 = *(const float4*)(Bact + (size_t)n*96 + k0 + 4);
    float r[8];
    r[0]=fmaxf(a0.x+b0.x,0.f); r[1]=fmaxf(a0.y+b0.y,0.f);
    r[2]=fmaxf(a0.z+b0.z,0.f); r[3]=fmaxf(a0.w+b0.w,0.f);
    r[4]=fmaxf(a1.x+b1.x,0.f); r[5]=fmaxf(a1.y+b1.y,0.f);
    r[6]=fmaxf(a1.z+b1.z,0.f); r[7]=fmaxf(a1.w+b1.w,0.f);
    #pragma unroll
    for (int j=0;j<8;j++){
      short hh,mm,ll; split3(r[j], hh, mm, ll);
      aH[kt][j]=hh; aM[kt][j]=mm; aL[kt][j]=ll;
    }
  }

  #pragma unroll 2
  for (int nt=0; nt<6; nt++){
    f32x4 acc = {0.f,0.f,0.f,0.f};
    #pragma unroll
    for (int kt=0; kt<3; kt++){
      bf16x8 WH = ((const bf16x8*)wf)[(size_t)((0*3+0)*18 + nt*3+kt)*64 + L];
      bf16x8 WM = ((const bf16x8*)wf)[(size_t)((0*3+1)*18 + nt*3+kt)*64 + L];
      bf16x8 WL = ((const bf16x8*)wf)[(size_t)((0*3+2)*18 + nt*3+kt)*64 + L];
      acc = __builtin_amdgcn_mfma_f32_16x16x32_bf16(aH[kt], WH, acc, 0,0,0);
      acc = __builtin_amdgcn_mfma_f32_16x16x32_bf16(aH[kt], WM, acc, 0,0,0);
      acc = __builtin_amdgcn_mfma_f32_16x16x32_bf16(aM[kt], WH, acc, 0,0,0);
      acc = __builtin_amdgcn_mfma_f32_16x16x32_bf16(aH[kt], WL, acc, 0,0,0);
      acc = __builtin_amdgcn_mfma_f32_16x16x32_bf16(aL[kt], WH, acc, 0,0,0);
      acc = __builtin_amdgcn_mfma_f32_16x16x32_bf16(aM[kt], WM, acc, 0,0,0);
    }
    int col = m + 16*nt;
    float bb = msgb[96 + col];
    #pragma unroll
    for (int r=0;r<4;r++)
      tile[w][(4*q + r)*100 + col] = fmaxf(acc[r] + bb, 0.f);
  }
  __syncthreads();

  bf16x8 hH[3], hM[3], hL[3];
  #pragma unroll
  for (int kt=0; kt<3; kt++){
    const float4* tp = (const float4*)&tile[w][m*100 + 32*kt + 8*q];
    float4 t0 = tp[0], t1 = tp[1];
    float r[8] = {t0.x,t0.y,t0.z,t0.w,t1.x,t1.y,t1.z,t1.w};
    #pragma unroll
    for (int j=0;j<8;j++){
      short hh,mm,ll; split3(r[j], hh, mm, ll);
      hH[kt][j]=hh; hM[kt][j]=mm; hL[kt][j]=ll;
    }
  }

  int lo_node = (w*16)/20;
  #pragma unroll 2
  for (int nt=0; nt<6; nt++){
    f32x4 acc = {0.f,0.f,0.f,0.f};
    #pragma unroll
    for (int kt=0; kt<3; kt++){
      bf16x8 WH = ((const bf16x8*)wf)[(size_t)((1*3+0)*18 + nt*3+kt)*64 + L];
      bf16x8 WM = ((const bf16x8*)wf)[(size_t)((1*3+1)*18 + nt*3+kt)*64 + L];
      bf16x8 WL = ((const bf16x8*)wf)[(size_t)((1*3+2)*18 + nt*3+kt)*64 + L];
      acc = __builtin_amdgcn_mfma_f32_16x16x32_bf16(hH[kt], WH, acc, 0,0,0);
      acc = __builtin_amdgcn_mfma_f32_16x16x32_bf16(hH[kt], WM, acc, 0,0,0);
      acc = __builtin_amdgcn_mfma_f32_16x16x32_bf16(hM[kt], WH, acc, 0,0,0);
      acc = __builtin_amdgcn_mfma_f32_16x16x32_bf16(hH[kt], WL, acc, 0,0,0);
      acc = __builtin_amdgcn_mfma_f32_16x16x32_bf16(hL[kt], WH, acc, 0,0,0);
      acc = __builtin_amdgcn_mfma_f32_16x16x32_bf16(hM[kt], WM, acc, 0,0,0);
    }
    int col = m + 16*nt;
    float bb = msgb[192 + col];
    float plo = 0.f, phi = 0.f;
    #pragma unroll
    for (int r=0;r<4;r++){
      int s = w*16 + 4*q + r;
      float o = fmaxf(acc[r] + bb, 0.f);
      if (s/20 == lo_node) plo += o; else phi += o;
    }
    plo += __shfl_xor(plo, 16); plo += __shfl_xor(plo, 32);
    phi += __shfl_xor(phi, 16); phi += __shfl_xor(phi, 32);
    if (L < 16){ part[w][0][col] = plo; part[w][1][col] = phi; }
  }
  __syncthreads();
  float* s2 = ws + O_S2;
  for (int idx = threadIdx.x; idx < 384; idx += 320){
    int nd = idx/96, col = idx%96;
    float s = 0.f;
    #pragma unroll
    for (int w2=0; w2<5; w2++){
      int lo = (w2*16)/20, hi = (w2*16+15)/20;
      if (lo == nd)       s += part[w2][0][col];
      else if (hi == nd)  s += part[w2][1][col];
    }
    s2[(size_t)(blockIdx.x*4+nd)*96 + col] = s;
  }
}

// ---------- hybrid LSTM: MFMA gates (3 separate K=96 GEMMs) + verbatim r7 scalar rest ----------
// block = 192 thr = 3 waves, 16 nodes. Wave w computes n-tiles [w*8, w*8+8).
__global__ __launch_bounds__(192) void k_lstm(float* ws, const int* labels,
                                              const float* msgb, const float* outW,
                                              const float* outb, float* out, int t)
{
  __shared__ float gbuf[16*384];   // full gate preacts: row=node slot, col=gate feature
  __shared__ float lh[16*97];
  __shared__ float lgt[160];
  int tid = threadIdx.x;
  int n0b = blockIdx.x*16;
  const float hs = (t == 0) ? 0.f : 1.f;  // scan carry rh starts at 0, not x

  { // ---- MFMA gates phase: gates = x@Wihx^T + s2@Wcomb^T + (hs*h)@Whh^T + GB
    int w = tid >> 6, L = tid & 63;
    int m = L & 15, q = L >> 4;
    int node = n0b + m;
    bf16x8 AF[3][3][3];  // [mat][lev][kt], mat: 0=x 1=s2 2=h
    #pragma unroll
    for (int kt=0; kt<3; kt++){
      int off = 32*kt + 8*q;
      #pragma unroll
      for (int mat=0; mat<3; mat++){
        const float* src = (mat==0 ? ws+O_X : (mat==1 ? ws+O_S2 : ws+O_H))
                           + (size_t)node*96 + off;
        float sc = (mat==2) ? hs : 1.f;
        float4 v0 = *(const float4*)src;
        float4 v1 = *(const float4*)(src+4);
        float r[8] = {v0.x*sc,v0.y*sc,v0.z*sc,v0.w*sc,v1.x*sc,v1.y*sc,v1.z*sc,v1.w*sc};
        #pragma unroll
        for (int j=0;j<8;j++){
          short hh,mm,ll; split3(r[j], hh, mm, ll);
          AF[mat][0][kt][j]=hh; AF[mat][1][kt][j]=mm; AF[mat][2][kt][j]=ll;
        }
      }
    }
    const bf16x8* GF = (const bf16x8*)(ws + O_GF);
    #pragma unroll 1
    for (int i8=0; i8<8; i8++){
      int nt = w*8 + i8;
      f32x4 acc = {0.f,0.f,0.f,0.f};
      #pragma unroll
      for (int mat=0; mat<3; mat++){
        #pragma unroll
        for (int kt=0; kt<3; kt++){
          bf16x8 WH = GF[((size_t)(mat*3+0)*72 + nt*3+kt)*64 + L];
          bf16x8 WM = GF[((size_t)(mat*3+1)*72 + nt*3+kt)*64 + L];
          bf16x8 WL = GF[((size_t)(mat*3+2)*72 + nt*3+kt)*64 + L];
          acc = __builtin_amdgcn_mfma_f32_16x16x32_bf16(AF[mat][0][kt], WH, acc, 0,0,0);
          acc = __builtin_amdgcn_mfma_f32_16x16x32_bf16(AF[mat][0][kt], WM, acc, 0,0,0);
          acc = __builtin_amdgcn_mfma_f32_16x16x32_bf16(AF[mat][1][kt], WH, acc, 0,0,0);
          acc = __builtin_amdgcn_mfma_f32_16x16x32_bf16(AF[mat][0][kt], WL, acc, 0,0,0);
          acc = __builtin_amdgcn_mfma_f32_16x16x32_bf16(AF[mat][2][kt], WH, acc, 0,0,0);
          acc = __builtin_amdgcn_mfma_f32_16x16x32_bf16(AF[mat][1][kt], WM, acc, 0,0,0);
        }
      }
      int col = m + 16*nt;               // C-layout: col=lane&15(+16nt), row=4q+r = node slot
      float gb = ws[O_GB + col];
      #pragma unroll
      for (int r=0;r<4;r++)
        gbuf[(4*q+r)*384 + col] = acc[r] + gb;
    }
  }
  __syncthreads();

  // ---- scalar remainder (verbatim r7-passing structure)
  int g = tid/96, j = tid%96;
  int n0 = n0b + g*8;
  float* h = ws + O_H; float* c = ws + O_C;

  float a0[8],a1[8],a2[8],a3[8];
  #pragma unroll
  for (int i=0;i<8;i++){
    int s = g*8+i;
    a0[i]=gbuf[s*384       + j];
    a1[i]=gbuf[s*384 +  96 + j];
    a2[i]=gbuf[s*384 + 192 + j];
    a3[i]=gbuf[s*384 + 288 + j];
  }
  float nh[8], ncv[8];
  #pragma unroll
  for (int i=0;i<8;i++){
    int n=n0+i;
    float ig=sigm(a0[i]), fg=sigm(a1[i]), gg=tanhf(a2[i]), og=sigm(a3[i]);
    float cv = c[(size_t)n*96+j];
    float nc = fg*cv + ig*gg;
    float nv = og*tanhf(nc);
    ncv[i]=nc; nh[i]=nv;
    lh[(g*8+i)*97 + j] = nv;
  }
  __syncthreads();
  #pragma unroll
  for (int i=0;i<8;i++){ int n=n0+i; c[(size_t)n*96+j]=ncv[i]; h[(size_t)n*96+j]=nh[i]; }

  const float* WA = ws + O_W0AT; const float* WB = ws + O_W0BT;
  float aa[8],ab[8];
  #pragma unroll
  for (int i=0;i<8;i++){ aa[i]=0.f; ab[i]=0.f; }
  #pragma unroll 2
  for (int k=0;k<96;k++){
    float wa=WA[k*96+j], wb=WB[k*96+j];
    #pragma unroll
    for (int i=0;i<8;i++){
      float hv = lh[(g*8+i)*97 + k];
      aa[i]=fmaf(wa,hv,aa[i]); ab[i]=fmaf(wb,hv,ab[i]);
    }
  }
  float* Aa=ws+O_A; float* Bb=ws+O_BV;
  float b0v = msgb[j];
  #pragma unroll
  for (int i=0;i<8;i++){ int n=n0+i; Aa[(size_t)n*96+j]=aa[i]; Bb[(size_t)n*96+j]=ab[i]+b0v; }

  if (j < 80){
    int ln = j/10, cls = j%10;
    int n = n0 + ln;
    float q0=outb[cls], q1=0.f, q2=0.f, q3=0.f;
    const float* hr = &lh[(g*8+ln)*97];
    #pragma unroll
    for (int k=0;k<96;k+=4){
      q0=fmaf(outW[cls*96+k  ],hr[k  ],q0); q1=fmaf(outW[cls*96+k+1],hr[k+1],q1);
      q2=fmaf(outW[cls*96+k+2],hr[k+2],q2); q3=fmaf(outW[cls*96+k+3],hr[k+3],q3);
    }
    float lg = (q0+q1)+(q2+q3);
    lgt[(g*8+ln)*10 + cls] = lg;
    out[165889 + ((size_t)t*NN + n)*10 + cls] = lg;
  }
  __syncthreads();
  if (j < 8){
    int n = n0 + j;
    const float* L = &lgt[(g*8+j)*10];
    float m = L[0]; int bi = 0;
    #pragma unroll
    for (int cc=1;cc<10;cc++){ if (L[cc] > m){ m=L[cc]; bi=cc; } }
    float se = 0.f;
    #pragma unroll
    for (int cc=0;cc<10;cc++) se += expf(L[cc]-m);
    int lab = labels[n];
    float lp = L[lab] - m - logf(se);
    atomicAdd(ws + O_LOSS, -lp);
    out[t*NN + n] = (float)bi;
  }
}

__global__ void k_final(float* ws, float* out){
  if (threadIdx.x == 0 && blockIdx.x == 0)
    out[165888] = ws[O_LOSS] / (float)(TT*NN);
}

extern "C" void kernel_launch(void* const* d_in, const int* in_sizes, int n_in,
                              void* d_out, int out_size, void* d_ws, size_t ws_size,
                              hipStream_t stream)
{
  (void)in_sizes; (void)n_in; (void)out_size; (void)ws_size;
  const int* q      = (const int*)d_in[0];
  const int* row    = (const int*)d_in[1];
  const int* col    = (const int*)d_in[2];
  const int* labels = (const int*)d_in[3];
  const int* dst    = (const int*)d_in[5];
  const float* demb  = (const float*)d_in[6];
  const float* remb  = (const float*)d_in[7];
  const float* cemb  = (const float*)d_in[8];
  const float* inW0  = (const float*)d_in[9];
  const float* inW   = (const float*)d_in[10];
  const float* inb   = (const float*)d_in[11];
  const float* msgW0 = (const float*)d_in[12];
  const float* msgW  = (const float*)d_in[13];
  const float* msgb  = (const float*)d_in[14];
  const float* Wih   = (const float*)d_in[15];
  const float* Whh   = (const float*)d_in[16];
  const float* outW  = (const float*)d_in[17];
  const float* outb  = (const float*)d_in[18];

  float* ws  = (float*)d_ws;
  float* out = (float*)d_out;

  hipLaunchKernelGGL(k_convert, dim3(199), dim3(256), 0, stream, ws, msgW0, inW0, inW);
  hipLaunchKernelGGL(k_gb, dim3(2), dim3(256), 0, stream, ws, Wih, msgb);
  hipLaunchKernelGGL(k_gfrag, dim3(162), dim3(256), 0, stream, ws, Wih, Whh, msgW);
  hipLaunchKernelGGL(k_wfrag, dim3(27), dim3(256), 0, stream, ws, msgW);
  hipLaunchKernelGGL(k_input, dim3(648), dim3(192), 0, stream,
                     ws, q, row, col, demb, remb, cemb, inb, msgb);
  for (int t=0; t<TT; ++t){
    hipLaunchKernelGGL(k_edge, dim3(EE/80), dim3(320), 0, stream, ws, dst, msgb);
    hipLaunchKernelGGL(k_lstm, dim3(648), dim3(192), 0, stream,
                       ws, labels, msgb, outW, outb, out, t);
  }
  hipLaunchKernelGGL(k_final, dim3(1), dim3(64), 0, stream, ws, out);
}

// Round 12
// 3139.541 us; speedup vs baseline: 1.0174x; 1.0174x over previous
//
#include <hip/hip_runtime.h>

#define NN 10368
#define EE 207360
#define TT 16

// ---- workspace layout (float offsets) ---- persistent end = 6,184,336 floats = 24.74 MB
#define O_W0AT    0
#define O_W0BT    9216
#define O_GB      18432
#define O_LOSS    18816
#define O_H       18832
#define O_C       (O_H  + NN*96)
#define O_A       (O_C  + NN*96)
#define O_BV      (O_A  + NN*96)
#define O_S2      (O_BV + NN*96)
#define O_X       (O_S2 + NN*96)
#define O_WFRAG   (O_X  + NN*96)      // edge frags: 55296 shorts = 27648 floats
#define O_GF      (O_WFRAG + 27648)   // gate frags: 3mat x 3lev x 72tiles x 512 shorts = 165888 floats
// prep-only aliases into S2 (written by k_convert, consumed by k_input, dead before k_edge):
#define O_WIN0T   (O_S2)              // 4608
#define O_WINT    (O_S2 + 4608)       // 27648

using bf16x8 = __attribute__((ext_vector_type(8))) short;
using f32x4  = __attribute__((ext_vector_type(4))) float;

__device__ __forceinline__ float sigm(float x){ return 1.f/(1.f + expf(-x)); }

__device__ __forceinline__ unsigned rne_bf16(float f){
  unsigned u = __float_as_uint(f);
  u += 0x7fffu + ((u >> 16) & 1u);
  return u >> 16;
}
__device__ __forceinline__ void split3(float x, short& h, short& m, short& l){
  unsigned uh = rne_bf16(x); h = (short)uh;
  float fh = __uint_as_float(uh << 16);
  float r1 = x - fh;
  unsigned um = rne_bf16(r1); m = (short)um;
  float fm = __uint_as_float(um << 16);
  float r2 = r1 - fm;
  l = (short)rne_bf16(r2);
}

// ---------- prep: weight transposes + loss zero ----------
__global__ void k_convert(float* ws, const float* msgW0,
                          const float* inW0, const float* inW)
{
  int i = blockIdx.x*256 + threadIdx.x;
  if (i < 9216){ int k=i/96, j=i%96; ws[O_W0AT+i] = msgW0[j*192+k];    return; } i -= 9216;
  if (i < 9216){ int k=i/96, j=i%96; ws[O_W0BT+i] = msgW0[j*192+96+k]; return; } i -= 9216;
  if (i < 4608){ int k=i/96, j=i%96; ws[O_WIN0T+i] = inW0[j*48+k];     return; } i -= 4608;
  if (i < 27648){ int l=i/9216, r=i%9216; int k=r/96, j=r%96;
                  ws[O_WINT+i] = inW[l*9216 + j*96 + k];               return; } i -= 27648;
  if (i == 0){ ws[O_LOSS] = 0.f; }
}

// ---------- gate bias fold: GB = 20 * W_ihm @ msg_b[3] ----------
__global__ void k_gb(float* ws, const float* Wih, const float* msgb)
{
  int j = blockIdx.x*256 + threadIdx.x;
  if (j >= 384) return;
  float g = 0.f;
  for (int r=0;r<96;r++) g = fmaf(Wih[j*192+96+r], msgb[288+r], g);
  ws[O_GB + j] = 20.f * g;
}

// ---------- gate weight frags (r11-verified): 3 matrices [384 x 96] ----------
__global__ void k_gfrag(float* ws, const float* Wih, const float* Whh, const float* msgW)
{
  int idx = blockIdx.x*256 + threadIdx.x;
  if (idx >= 3*3*72*64) return;
  int lane = idx & 63;
  int tile = (idx >> 6) % 72;
  int lev  = (idx >> 6) / 72 % 3;
  int mat  = (idx >> 6) / 216;
  int nt = tile/3, kt = tile%3;
  int nout = (lane & 15) + 16*nt;
  int q = lane >> 4;
  unsigned short* dstp = (unsigned short*)(ws + O_GF) + (size_t)idx*8;
  for (int j=0;j<8;j++){
    int k = 32*kt + 8*q + j;
    float wv;
    if (mat == 0)      wv = Wih[nout*192 + k];
    else if (mat == 2) wv = Whh[nout*96 + k];
    else {
      float a = 0.f;
      for (int r=0;r<96;r++) a = fmaf(Wih[nout*192+96+r], msgW[2*9216 + r*96 + k], a);
      wv = a;
    }
    short h,m,l; split3(wv, h, m, l);
    dstp[j] = (unsigned short)(lev==0 ? h : (lev==1 ? m : l));
  }
}

// ---------- msg W1/W2 -> bf16 split-3 B-fragments (edge kernel, verified) ----------
__global__ void k_wfrag(float* ws, const float* msgW)
{
  int idx = blockIdx.x*256 + threadIdx.x;
  if (idx >= 2*3*18*64) return;
  int lane = idx & 63;
  int tile = (idx >> 6) % 18;
  int lev  = (idx >> 6) / 18 % 3;
  int layer= (idx >> 6) / 54;
  int nt = tile/3, kt = tile%3;
  int nout = (lane & 15) + 16*nt;
  int q = lane >> 4;
  unsigned short* wf = (unsigned short*)(ws + O_WFRAG);
  unsigned short* dstp = wf + (size_t)(((layer*3+lev)*18 + tile)*64 + lane)*8;
  const float* W = msgW + layer*9216;
  for (int j=0;j<8;j++){
    float wv = W[nout*96 + 32*kt + 8*q + j];
    short h,m,l; split3(wv, h, m, l);
    dstp[j] = (unsigned short)(lev==0 ? h : (lev==1 ? m : l));
  }
}

// ---------- input MLP (j-parallel) + fused step-0 A/B (verified) ----------
__global__ __launch_bounds__(192) void k_input(float* ws,
    const int* q, const int* row, const int* col,
    const float* demb, const float* remb, const float* cemb,
    const float* inb, const float* msgb)
{
  __shared__ float ein[2][8*49];
  __shared__ float hb[2][8*97];
  int tid = threadIdx.x; int g = tid/96, j = tid%96;
  int nq = blockIdx.x*2 + g; int n0 = nq*8;

  for (int idx=j; idx<384; idx+=96){
    int i = idx/48, f = idx%48; int n = n0+i;
    float v;
    if (f < 16)      v = demb[q[n]*16 + f];
    else if (f < 32) v = remb[row[n]*16 + (f-16)];
    else             v = cemb[col[n]*16 + (f-32)];
    ein[g][i*49+f] = v;
  }
  __syncthreads();

  float acc[8];
  {
    const float* W0T = ws + O_WIN0T;
    float b0 = inb[j];
    #pragma unroll
    for (int i=0;i<8;i++) acc[i]=b0;
    #pragma unroll 2
    for (int k=0;k<48;k++){
      float w = W0T[k*96+j];
      #pragma unroll
      for (int i=0;i<8;i++) acc[i] = fmaf(w, ein[g][i*49+k], acc[i]);
    }
    #pragma unroll
    for (int i=0;i<8;i++) hb[g][i*97+j] = fmaxf(acc[i], 0.f);
  }
  __syncthreads();

  for (int l=0;l<3;l++){
    const float* WT = ws + O_WINT + l*9216;
    float bl = inb[(l+1)*96 + j];
    #pragma unroll
    for (int i=0;i<8;i++) acc[i]=bl;
    #pragma unroll 2
    for (int k=0;k<96;k++){
      float w = WT[k*96+j];
      #pragma unroll
      for (int i=0;i<8;i++) acc[i] = fmaf(w, hb[g][i*97+k], acc[i]);
    }
    __syncthreads();
    if (l < 2){
      #pragma unroll
      for (int i=0;i<8;i++) hb[g][i*97+j] = fmaxf(acc[i], 0.f);
    } else {
      #pragma unroll
      for (int i=0;i<8;i++) hb[g][i*97+j] = acc[i];
    }
    __syncthreads();
  }

  float* h = ws + O_H; float* c = ws + O_C; float* x = ws + O_X;
  #pragma unroll
  for (int i=0;i<8;i++){
    int n = n0+i;
    float vv = hb[g][i*97+j];
    h[n*96+j]=vv; x[n*96+j]=vv; c[n*96+j]=0.f;
  }
  const float* WA = ws + O_W0AT; const float* WB = ws + O_W0BT;
  float aa[8], ab[8];
  #pragma unroll
  for (int i=0;i<8;i++){ aa[i]=0.f; ab[i]=0.f; }
  #pragma unroll 2
  for (int k=0;k<96;k++){
    float wa=WA[k*96+j], wb=WB[k*96+j];
    #pragma unroll
    for (int i=0;i<8;i++){
      float hv = hb[g][i*97+k];
      aa[i]=fmaf(wa,hv,aa[i]); ab[i]=fmaf(wb,hv,ab[i]);
    }
  }
  float* A=ws+O_A; float* Bv=ws+O_BV;
  float b0v = msgb[j];
  #pragma unroll
  for (int i=0;i<8;i++){ int n=n0+i; A[n*96+j]=aa[i]; Bv[n*96+j]=ab[i]+b0v; }
}

// ---------- per-step edge MLP via bf16 split-3 MFMA, 4 nodes/block (verified) ----------
__global__ __launch_bounds__(320) void k_edge(float* ws, const int* dst, const float* msgb)
{
  __shared__ float tile[5][16*100];
  __shared__ float part[5][2][96];
  int w = threadIdx.x >> 6;
  int L = threadIdx.x & 63;
  int m = L & 15, q = L >> 4;
  int gs = w*16 + m;
  int e  = blockIdx.x*80 + gs;
  int v  = dst[e];
  int n  = blockIdx.x*4 + gs/20;

  const float* Aact = ws + O_A;
  const float* Bact = ws + O_BV;
  const unsigned short* wf = (const unsigned short*)(ws + O_WFRAG);

  bf16x8 aH[3], aM[3], aL[3];
  #pragma unroll
  for (int kt=0; kt<3; kt++){
    int k0 = 32*kt + 8*q;
    float4 a0 = *(const float4*)(Aact + (size_t)v*96 + k0);
    float4 a1 = *(const float4*)(Aact + (size_t)v*96 + k0 + 4);
    float4 b0 = *(const float4*)(Bact + (size_t)n*96 + k0);
    float4 b1 = *(const float4*)(Bact + (size_t)n*96 + k0 + 4);
    float r[8];
    r[0]=fmaxf(a0.x+b0.x,0.f); r[1]=fmaxf(a0.y+b0.y,0.f);
    r[2]=fmaxf(a0.z+b0.z,0.f); r[3]=fmaxf(a0.w+b0.w,0.f);
    r[4]=fmaxf(a1.x+b1.x,0.f); r[5]=fmaxf(a1.y+b1.y,0.f);
    r[6]=fmaxf(a1.z+b1.z,0.f); r[7]=fmaxf(a1.w+b1.w,0.f);
    #pragma unroll
    for (int j=0;j<8;j++){
      short hh,mm,ll; split3(r[j], hh, mm, ll);
      aH[kt][j]=hh; aM[kt][j]=mm; aL[kt][j]=ll;
    }
  }

  #pragma unroll 2
  for (int nt=0; nt<6; nt++){
    f32x4 acc = {0.f,0.f,0.f,0.f};
    #pragma unroll
    for (int kt=0; kt<3; kt++){
      bf16x8 WH = ((const bf16x8*)wf)[(size_t)((0*3+0)*18 + nt*3+kt)*64 + L];
      bf16x8 WM = ((const bf16x8*)wf)[(size_t)((0*3+1)*18 + nt*3+kt)*64 + L];
      bf16x8 WL = ((const bf16x8*)wf)[(size_t)((0*3+2)*18 + nt*3+kt)*64 + L];
      acc = __builtin_amdgcn_mfma_f32_16x16x32_bf16(aH[kt], WH, acc, 0,0,0);
      acc = __builtin_amdgcn_mfma_f32_16x16x32_bf16(aH[kt], WM, acc, 0,0,0);
      acc = __builtin_amdgcn_mfma_f32_16x16x32_bf16(aM[kt], WH, acc, 0,0,0);
      acc = __builtin_amdgcn_mfma_f32_16x16x32_bf16(aH[kt], WL, acc, 0,0,0);
      acc = __builtin_amdgcn_mfma_f32_16x16x32_bf16(aL[kt], WH, acc, 0,0,0);
      acc = __builtin_amdgcn_mfma_f32_16x16x32_bf16(aM[kt], WM, acc, 0,0,0);
    }
    int col = m + 16*nt;
    float bb = msgb[96 + col];
    #pragma unroll
    for (int r=0;r<4;r++)
      tile[w][(4*q + r)*100 + col] = fmaxf(acc[r] + bb, 0.f);
  }
  __syncthreads();

  bf16x8 hH[3], hM[3], hL[3];
  #pragma unroll
  for (int kt=0; kt<3; kt++){
    const float4* tp = (const float4*)&tile[w][m*100 + 32*kt + 8*q];
    float4 t0 = tp[0], t1 = tp[1];
    float r[8] = {t0.x,t0.y,t0.z,t0.w,t1.x,t1.y,t1.z,t1.w};
    #pragma unroll
    for (int j=0;j<8;j++){
      short hh,mm,ll; split3(r[j], hh, mm, ll);
      hH[kt][j]=hh; hM[kt][j]=mm; hL[kt][j]=ll;
    }
  }

  int lo_node = (w*16)/20;
  #pragma unroll 2
  for (int nt=0; nt<6; nt++){
    f32x4 acc = {0.f,0.f,0.f,0.f};
    #pragma unroll
    for (int kt=0; kt<3; kt++){
      bf16x8 WH = ((const bf16x8*)wf)[(size_t)((1*3+0)*18 + nt*3+kt)*64 + L];
      bf16x8 WM = ((const bf16x8*)wf)[(size_t)((1*3+1)*18 + nt*3+kt)*64 + L];
      bf16x8 WL = ((const bf16x8*)wf)[(size_t)((1*3+2)*18 + nt*3+kt)*64 + L];
      acc = __builtin_amdgcn_mfma_f32_16x16x32_bf16(hH[kt], WH, acc, 0,0,0);
      acc = __builtin_amdgcn_mfma_f32_16x16x32_bf16(hH[kt], WM, acc, 0,0,0);
      acc = __builtin_amdgcn_mfma_f32_16x16x32_bf16(hM[kt], WH, acc, 0,0,0);
      acc = __builtin_amdgcn_mfma_f32_16x16x32_bf16(hH[kt], WL, acc, 0,0,0);
      acc = __builtin_amdgcn_mfma_f32_16x16x32_bf16(hL[kt], WH, acc, 0,0,0);
      acc = __builtin_amdgcn_mfma_f32_16x16x32_bf16(hM[kt], WM, acc, 0,0,0);
    }
    int col = m + 16*nt;
    float bb = msgb[192 + col];
    float plo = 0.f, phi = 0.f;
    #pragma unroll
    for (int r=0;r<4;r++){
      int s = w*16 + 4*q + r;
      float o = fmaxf(acc[r] + bb, 0.f);
      if (s/20 == lo_node) plo += o; else phi += o;
    }
    plo += __shfl_xor(plo, 16); plo += __shfl_xor(plo, 32);
    phi += __shfl_xor(phi, 16); phi += __shfl_xor(phi, 32);
    if (L < 16){ part[w][0][col] = plo; part[w][1][col] = phi; }
  }
  __syncthreads();
  float* s2 = ws + O_S2;
  for (int idx = threadIdx.x; idx < 384; idx += 320){
    int nd = idx/96, col = idx%96;
    float s = 0.f;
    #pragma unroll
    for (int w2=0; w2<5; w2++){
      int lo = (w2*16)/20, hi = (w2*16+15)/20;
      if (lo == nd)       s += part[w2][0][col];
      else if (hi == nd)  s += part[w2][1][col];
    }
    s2[(size_t)(blockIdx.x*4+nd)*96 + col] = s;
  }
}

// ---------- LSTM: MFMA gates with in-register elementwise (no gbuf) + scalar rest ----------
// block 192 = 3 waves, 16 nodes. Wave w owns jg in {2w,2w+1}: n-tiles {jg,jg+6,jg+12,jg+18}
// = the full i,f,g,o quadruple for features m+16jg -> elementwise on accumulators.
__global__ __launch_bounds__(192) void k_lstm(float* ws, const int* labels,
                                              const float* msgb, const float* outW,
                                              const float* outb, float* out, int t)
{
  __shared__ float tile[16*100];   // nh, C-layout: row=node slot, col=feature
  __shared__ float lgt[160];
  int tid = threadIdx.x;
  int n0b = blockIdx.x*16;
  const float hs = (t == 0) ? 0.f : 1.f;  // scan carry rh starts at 0, not x

  { // ---- phase A: gates = x@Wihx^T + s2@Wcomb^T + (hs*h)@Whh^T + GB, then LSTM elementwise
    int w = tid >> 6, L = tid & 63;
    int m = L & 15, q = L >> 4;
    int node = n0b + m;
    bf16x8 AF[3][3][3];  // [mat][lev][kt]
    #pragma unroll
    for (int kt=0; kt<3; kt++){
      int off = 32*kt + 8*q;
      #pragma unroll
      for (int mat=0; mat<3; mat++){
        const float* src = (mat==0 ? ws+O_X : (mat==1 ? ws+O_S2 : ws+O_H))
                           + (size_t)node*96 + off;
        float sc = (mat==2) ? hs : 1.f;
        float4 v0 = *(const float4*)src;
        float4 v1 = *(const float4*)(src+4);
        float r[8] = {v0.x*sc,v0.y*sc,v0.z*sc,v0.w*sc,v1.x*sc,v1.y*sc,v1.z*sc,v1.w*sc};
        #pragma unroll
        for (int j=0;j<8;j++){
          short hh,mm,ll; split3(r[j], hh, mm, ll);
          AF[mat][0][kt][j]=hh; AF[mat][1][kt][j]=mm; AF[mat][2][kt][j]=ll;
        }
      }
    }
    const bf16x8* GF = (const bf16x8*)(ws + O_GF);
    float* cg = ws + O_C;
    #pragma unroll 1
    for (int jj=0; jj<2; jj++){
      int jg = 2*w + jj;
      f32x4 acc[4];
      #pragma unroll
      for (int g2=0; g2<4; g2++){
        float gb = ws[O_GB + m + 16*(jg + 6*g2)];
        acc[g2] = (f32x4){gb,gb,gb,gb};
      }
      #pragma unroll
      for (int mat=0; mat<3; mat++){
        #pragma unroll
        for (int kt=0; kt<3; kt++){
          #pragma unroll
          for (int g2=0; g2<4; g2++){
            int nt = jg + 6*g2;
            bf16x8 WH = GF[((size_t)(mat*3+0)*72 + nt*3+kt)*64 + L];
            bf16x8 WM = GF[((size_t)(mat*3+1)*72 + nt*3+kt)*64 + L];
            bf16x8 WL = GF[((size_t)(mat*3+2)*72 + nt*3+kt)*64 + L];
            acc[g2] = __builtin_amdgcn_mfma_f32_16x16x32_bf16(AF[mat][0][kt], WH, acc[g2], 0,0,0);
            acc[g2] = __builtin_amdgcn_mfma_f32_16x16x32_bf16(AF[mat][0][kt], WM, acc[g2], 0,0,0);
            acc[g2] = __builtin_amdgcn_mfma_f32_16x16x32_bf16(AF[mat][1][kt], WH, acc[g2], 0,0,0);
            acc[g2] = __builtin_amdgcn_mfma_f32_16x16x32_bf16(AF[mat][0][kt], WL, acc[g2], 0,0,0);
            acc[g2] = __builtin_amdgcn_mfma_f32_16x16x32_bf16(AF[mat][2][kt], WH, acc[g2], 0,0,0);
            acc[g2] = __builtin_amdgcn_mfma_f32_16x16x32_bf16(AF[mat][1][kt], WM, acc[g2], 0,0,0);
          }
        }
      }
      int f = m + 16*jg;
      #pragma unroll
      for (int r=0;r<4;r++){
        int slot = 4*q + r;
        int nd = n0b + slot;
        float ig = sigm(acc[0][r]);
        float fg = sigm(acc[1][r]);
        float gg = tanhf(acc[2][r]);
        float og = sigm(acc[3][r]);
        float cv = cg[(size_t)nd*96 + f];
        float nc = fg*cv + ig*gg;
        float nv = og*tanhf(nc);
        cg[(size_t)nd*96 + f] = nc;
        tile[slot*100 + f] = nv;
      }
    }
  }
  __syncthreads();

  // ---- phase B: h write (coalesced from tile) + scalar A/B + logits + loss
  int g = tid/96, j = tid%96;
  int n0 = n0b + g*8;
  float* h = ws + O_H;
  for (int idx = tid; idx < 1536; idx += 192){
    int sl = idx/96, f = idx%96;
    h[(size_t)(n0b+sl)*96 + f] = tile[sl*100 + f];
  }

  const float* WA = ws + O_W0AT; const float* WB = ws + O_W0BT;
  float aa[8],ab[8];
  #pragma unroll
  for (int i=0;i<8;i++){ aa[i]=0.f; ab[i]=0.f; }
  #pragma unroll 2
  for (int k=0;k<96;k++){
    float wa=WA[k*96+j], wb=WB[k*96+j];
    #pragma unroll
    for (int i=0;i<8;i++){
      float hv = tile[(g*8+i)*100 + k];
      aa[i]=fmaf(wa,hv,aa[i]); ab[i]=fmaf(wb,hv,ab[i]);
    }
  }
  float* Aa=ws+O_A; float* Bb=ws+O_BV;
  float b0v = msgb[j];
  #pragma unroll
  for (int i=0;i<8;i++){ int n=n0+i; Aa[(size_t)n*96+j]=aa[i]; Bb[(size_t)n*96+j]=ab[i]+b0v; }

  if (j < 80){
    int ln = j/10, cls = j%10;
    int n = n0 + ln;
    float q0=outb[cls], q1=0.f, q2=0.f, q3=0.f;
    const float* hr = &tile[(g*8+ln)*100];
    #pragma unroll
    for (int k=0;k<96;k+=4){
      q0=fmaf(outW[cls*96+k  ],hr[k  ],q0); q1=fmaf(outW[cls*96+k+1],hr[k+1],q1);
      q2=fmaf(outW[cls*96+k+2],hr[k+2],q2); q3=fmaf(outW[cls*96+k+3],hr[k+3],q3);
    }
    float lg = (q0+q1)+(q2+q3);
    lgt[(g*8+ln)*10 + cls] = lg;
    out[165889 + ((size_t)t*NN + n)*10 + cls] = lg;
  }
  __syncthreads();
  if (j < 8){
    int n = n0 + j;
    const float* L = &lgt[(g*8+j)*10];
    float m = L[0]; int bi = 0;
    #pragma unroll
    for (int cc=1;cc<10;cc++){ if (L[cc] > m){ m=L[cc]; bi=cc; } }
    float se = 0.f;
    #pragma unroll
    for (int cc=0;cc<10;cc++) se += expf(L[cc]-m);
    int lab = labels[n];
    float lp = L[lab] - m - logf(se);
    atomicAdd(ws + O_LOSS, -lp);
    out[t*NN + n] = (float)bi;
  }
}

__global__ void k_final(float* ws, float* out){
  if (threadIdx.x == 0 && blockIdx.x == 0)
    out[165888] = ws[O_LOSS] / (float)(TT*NN);
}

extern "C" void kernel_launch(void* const* d_in, const int* in_sizes, int n_in,
                              void* d_out, int out_size, void* d_ws, size_t ws_size,
                              hipStream_t stream)
{
  (void)in_sizes; (void)n_in; (void)out_size; (void)ws_size;
  const int* q      = (const int*)d_in[0];
  const int* row    = (const int*)d_in[1];
  const int* col    = (const int*)d_in[2];
  const int* labels = (const int*)d_in[3];
  const int* dst    = (const int*)d_in[5];
  const float* demb  = (const float*)d_in[6];
  const float* remb  = (const float*)d_in[7];
  const float* cemb  = (const float*)d_in[8];
  const float* inW0  = (const float*)d_in[9];
  const float* inW   = (const float*)d_in[10];
  const float* inb   = (const float*)d_in[11];
  const float* msgW0 = (const float*)d_in[12];
  const float* msgW  = (const float*)d_in[13];
  const float* msgb  = (const float*)d_in[14];
  const float* Wih   = (const float*)d_in[15];
  const float* Whh   = (const float*)d_in[16];
  const float* outW  = (const float*)d_in[17];
  const float* outb  = (const float*)d_in[18];

  float* ws  = (float*)d_ws;
  float* out = (float*)d_out;

  hipLaunchKernelGGL(k_convert, dim3(199), dim3(256), 0, stream, ws, msgW0, inW0, inW);
  hipLaunchKernelGGL(k_gb, dim3(2), dim3(256), 0, stream, ws, Wih, msgb);
  hipLaunchKernelGGL(k_gfrag, dim3(162), dim3(256), 0, stream, ws, Wih, Whh, msgW);
  hipLaunchKernelGGL(k_wfrag, dim3(27), dim3(256), 0, stream, ws, msgW);
  hipLaunchKernelGGL(k_input, dim3(648), dim3(192), 0, stream,
                     ws, q, row, col, demb, remb, cemb, inb, msgb);
  for (int t=0; t<TT; ++t){
    hipLaunchKernelGGL(k_edge, dim3(EE/80), dim3(320), 0, stream, ws, dst, msgb);
    hipLaunchKernelGGL(k_lstm, dim3(648), dim3(192), 0, stream,
                       ws, labels, msgb, outW, outb, out, t);
  }
  hipLaunchKernelGGL(k_final, dim3(1), dim3(64), 0, stream, ws, out);
}